// Round 3
// baseline (3448.275 us; speedup 1.0000x reference)
//
#include <hip/hip_runtime.h>

#define BN_EPS 1e-5f

// ---------------- CSR build ----------------

__global__ __launch_bounds__(256) void count_k(const int* __restrict__ dst, int E, int* __restrict__ cnt) {
    int i = blockIdx.x * 256 + threadIdx.x;
    if (i < E) atomicAdd(&cnt[dst[i]], 1);
}

__global__ __launch_bounds__(1024) void scan1_k(const int* __restrict__ cnt, int n, int* __restrict__ bsum) {
    __shared__ int sh[1024];
    int i = blockIdx.x * 1024 + threadIdx.x;
    sh[threadIdx.x] = (i < n) ? cnt[i] : 0;
    __syncthreads();
    for (int s = 512; s > 0; s >>= 1) {
        if (threadIdx.x < (unsigned)s) sh[threadIdx.x] += sh[threadIdx.x + s];
        __syncthreads();
    }
    if (threadIdx.x == 0) bsum[blockIdx.x] = sh[0];
}

__global__ void scan2_k(int* bsum, int nb, int* rowptr, int n, int E) {
    if (threadIdx.x == 0 && blockIdx.x == 0) {
        int run = 0;
        for (int i = 0; i < nb; ++i) { int v = bsum[i]; bsum[i] = run; run += v; }
        rowptr[n] = E;
    }
}

__global__ __launch_bounds__(1024) void scan3_k(const int* __restrict__ cnt, int n, const int* __restrict__ boff,
                                                int* __restrict__ rowptr, int* __restrict__ nxt) {
    __shared__ int sh[1024];
    int i = blockIdx.x * 1024 + threadIdx.x;
    int v = (i < n) ? cnt[i] : 0;
    sh[threadIdx.x] = v;
    __syncthreads();
    for (int s = 1; s < 1024; s <<= 1) {
        int t = (threadIdx.x >= (unsigned)s) ? sh[threadIdx.x - s] : 0;
        __syncthreads();
        sh[threadIdx.x] += t;
        __syncthreads();
    }
    if (i < n) {
        int ex = boff[blockIdx.x] + sh[threadIdx.x] - v;
        rowptr[i] = ex;
        nxt[i] = ex;
    }
}

__global__ __launch_bounds__(256) void scatter_k(const int* __restrict__ src, const int* __restrict__ dst, int E,
                                                 int* __restrict__ nxt, int* __restrict__ ssrc) {
    int i = blockIdx.x * 256 + threadIdx.x;
    if (i < E) {
        int d = dst[i];
        int p = atomicAdd(&nxt[d], 1);
        ssrc[p] = src[i];
    }
}

// ---------------- helpers ----------------

static __device__ __forceinline__ unsigned short f2bf(float f) {
    unsigned u = __float_as_uint(f);
    unsigned r = (u + 0x7FFFu + ((u >> 16) & 1u)) >> 16;  // RNE
    return (unsigned short)r;
}
static __device__ __forceinline__ float bf_lo(unsigned u) { return __uint_as_float(u << 16); }
static __device__ __forceinline__ float bf_hi(unsigned u) { return __uint_as_float(u & 0xFFFF0000u); }

// ---------------- GEMM: H(bf16) = f(X) @ W, f = identity (MODE 0) or BN+ReLU (MODE 1) ----------------

template <int MODE>
__global__ __launch_bounds__(256) void gemm_k(const float* __restrict__ X, const float* __restrict__ W,
                                              unsigned short* __restrict__ H, const float* __restrict__ ss, int n) {
    __shared__ float As[128][36];
    __shared__ float Bs[32][128];
    int tid = threadIdx.x;
    int rg = tid & 15;
    int cg = tid >> 4;
    int rowBase = blockIdx.x * 128;

    float acc[8][8];
#pragma unroll
    for (int i = 0; i < 8; ++i)
#pragma unroll
        for (int j = 0; j < 8; ++j) acc[i][j] = 0.f;

    for (int k0 = 0; k0 < 128; k0 += 32) {
#pragma unroll
        for (int t = 0; t < 4; ++t) {
            int idx = tid + t * 256;
            int r = idx >> 3;
            int c4 = (idx & 7) * 4;
            int gr = rowBase + r;
            float4 v = make_float4(0.f, 0.f, 0.f, 0.f);
            if (gr < n) v = *(const float4*)(X + (size_t)gr * 128 + k0 + c4);
            if (MODE) {
                int c = k0 + c4;
                v.x = fmaxf(fmaf(v.x, ss[c + 0], ss[128 + c + 0]), 0.f);
                v.y = fmaxf(fmaf(v.y, ss[c + 1], ss[128 + c + 1]), 0.f);
                v.z = fmaxf(fmaf(v.z, ss[c + 2], ss[128 + c + 2]), 0.f);
                v.w = fmaxf(fmaf(v.w, ss[c + 3], ss[128 + c + 3]), 0.f);
            }
            *(float4*)&As[r][c4] = v;
        }
#pragma unroll
        for (int t = 0; t < 4; ++t) {
            int idx = tid + t * 256;
            int r = idx >> 5;
            int c4 = (idx & 31) * 4;
            *(float4*)&Bs[r][c4] = *(const float4*)(W + (size_t)(k0 + r) * 128 + c4);
        }
        __syncthreads();

#pragma unroll
        for (int kk = 0; kk < 32; kk += 4) {
            float4 a[8];
#pragma unroll
            for (int i = 0; i < 8; ++i) a[i] = *(const float4*)&As[rg + 16 * i][kk];
#pragma unroll
            for (int t = 0; t < 4; ++t) {
                float4 wl = *(const float4*)&Bs[kk + t][cg * 8];
                float4 wh = *(const float4*)&Bs[kk + t][cg * 8 + 4];
#pragma unroll
                for (int i = 0; i < 8; ++i) {
                    float av = (t == 0) ? a[i].x : (t == 1) ? a[i].y : (t == 2) ? a[i].z : a[i].w;
                    acc[i][0] = fmaf(av, wl.x, acc[i][0]);
                    acc[i][1] = fmaf(av, wl.y, acc[i][1]);
                    acc[i][2] = fmaf(av, wl.z, acc[i][2]);
                    acc[i][3] = fmaf(av, wl.w, acc[i][3]);
                    acc[i][4] = fmaf(av, wh.x, acc[i][4]);
                    acc[i][5] = fmaf(av, wh.y, acc[i][5]);
                    acc[i][6] = fmaf(av, wh.z, acc[i][6]);
                    acc[i][7] = fmaf(av, wh.w, acc[i][7]);
                }
            }
        }
        __syncthreads();
    }

#pragma unroll
    for (int i = 0; i < 8; ++i) {
        int gr = rowBase + rg + 16 * i;
        if (gr < n) {
            uint4 pk;
            pk.x = (unsigned)f2bf(acc[i][0]) | ((unsigned)f2bf(acc[i][1]) << 16);
            pk.y = (unsigned)f2bf(acc[i][2]) | ((unsigned)f2bf(acc[i][3]) << 16);
            pk.z = (unsigned)f2bf(acc[i][4]) | ((unsigned)f2bf(acc[i][5]) << 16);
            pk.w = (unsigned)f2bf(acc[i][6]) | ((unsigned)f2bf(acc[i][7]) << 16);
            *(uint4*)(H + (size_t)gr * 128 + cg * 8) = pk;
        }
    }
}

// ---------------- Aggregation: out[n](f32) = sum_{e in CSR[n]} H_bf16[src[e]] ----------------
// One wave per node (grid-strided). Quarter-wave (16 lanes) per edge row:
// lane = sub*16 + fg; lane reads uint4 = 8 bf16 feats at col fg*8.
// One gather instruction covers 4 edges (1 KB); 16 edges in flight per round.

template <int MODE>
__global__ __launch_bounds__(256) void agg_k(const unsigned short* __restrict__ H, const int* __restrict__ rowptr,
                                             const int* __restrict__ ssrc, float* __restrict__ out,
                                             double* __restrict__ stats, int n) {
    int lane = threadIdx.x & 63;
    int sub = lane >> 4;       // 0..3: which edge of the 4-edge group
    int fg = lane & 15;        // feature group: cols fg*8 .. fg*8+7
    int wid = (blockIdx.x * 256 + threadIdx.x) >> 6;
    int nw = (gridDim.x * 256) >> 6;
    const unsigned short* hb = H + fg * 8;

    double s0 = 0, s1 = 0, s2 = 0, s3 = 0, q0 = 0, q1 = 0, q2 = 0, q3 = 0;

    for (int node = wid; node < n; node += nw) {
        int beg = rowptr[node], end = rowptr[node + 1];
        float a0 = 0, a1 = 0, a2 = 0, a3 = 0, a4 = 0, a5 = 0, a6 = 0, a7 = 0;

        for (int e = beg; e < end; e += 16) {
            int e0 = e + sub, e1 = e0 + 4, e2 = e0 + 8, e3 = e0 + 12;
            int i0 = 0, i1 = 0, i2 = 0, i3 = 0;
            bool p0 = e0 < end, p1 = e1 < end, p2 = e2 < end, p3 = e3 < end;
            if (p0) i0 = ssrc[e0];
            if (p1) i1 = ssrc[e1];
            if (p2) i2 = ssrc[e2];
            if (p3) i3 = ssrc[e3];
            uint4 v0 = make_uint4(0, 0, 0, 0), v1 = v0, v2 = v0, v3 = v0;
            if (p0) v0 = *(const uint4*)(hb + (size_t)i0 * 128);
            if (p1) v1 = *(const uint4*)(hb + (size_t)i1 * 128);
            if (p2) v2 = *(const uint4*)(hb + (size_t)i2 * 128);
            if (p3) v3 = *(const uint4*)(hb + (size_t)i3 * 128);
            a0 += bf_lo(v0.x) + bf_lo(v1.x) + bf_lo(v2.x) + bf_lo(v3.x);
            a1 += bf_hi(v0.x) + bf_hi(v1.x) + bf_hi(v2.x) + bf_hi(v3.x);
            a2 += bf_lo(v0.y) + bf_lo(v1.y) + bf_lo(v2.y) + bf_lo(v3.y);
            a3 += bf_hi(v0.y) + bf_hi(v1.y) + bf_hi(v2.y) + bf_hi(v3.y);
            a4 += bf_lo(v0.z) + bf_lo(v1.z) + bf_lo(v2.z) + bf_lo(v3.z);
            a5 += bf_hi(v0.z) + bf_hi(v1.z) + bf_hi(v2.z) + bf_hi(v3.z);
            a6 += bf_lo(v0.w) + bf_lo(v1.w) + bf_lo(v2.w) + bf_lo(v3.w);
            a7 += bf_hi(v0.w) + bf_hi(v1.w) + bf_hi(v2.w) + bf_hi(v3.w);
        }

        // combine the 4 sub-waves: lanes {fg, fg+16, fg+32, fg+48} hold partials of the same 8 feats
        a0 += __shfl_xor(a0, 16); a0 += __shfl_xor(a0, 32);
        a1 += __shfl_xor(a1, 16); a1 += __shfl_xor(a1, 32);
        a2 += __shfl_xor(a2, 16); a2 += __shfl_xor(a2, 32);
        a3 += __shfl_xor(a3, 16); a3 += __shfl_xor(a3, 32);
        a4 += __shfl_xor(a4, 16); a4 += __shfl_xor(a4, 32);
        a5 += __shfl_xor(a5, 16); a5 += __shfl_xor(a5, 32);
        a6 += __shfl_xor(a6, 16); a6 += __shfl_xor(a6, 32);
        a7 += __shfl_xor(a7, 16); a7 += __shfl_xor(a7, 32);

        if (MODE == 0) {
            if (sub == 0) {
                *(float4*)(out + (size_t)node * 128 + fg * 8) = make_float4(a0, a1, a2, a3);
                s0 += a0; q0 += (double)a0 * a0;
                s1 += a1; q1 += (double)a1 * a1;
                s2 += a2; q2 += (double)a2 * a2;
                s3 += a3; q3 += (double)a3 * a3;
            } else if (sub == 1) {
                *(float4*)(out + (size_t)node * 128 + fg * 8 + 4) = make_float4(a4, a5, a6, a7);
                s0 += a4; q0 += (double)a4 * a4;
                s1 += a5; q1 += (double)a5 * a5;
                s2 += a6; q2 += (double)a6 * a6;
                s3 += a7; q3 += (double)a7 * a7;
            }
        } else {
            // every lane holds complete sums for its 8 feats -> reduce over fg bits only
            float m = fmaxf(fmaxf(fmaxf(a0, a1), fmaxf(a2, a3)), fmaxf(fmaxf(a4, a5), fmaxf(a6, a7)));
            m = fmaxf(m, __shfl_xor(m, 1));
            m = fmaxf(m, __shfl_xor(m, 2));
            m = fmaxf(m, __shfl_xor(m, 4));
            m = fmaxf(m, __shfl_xor(m, 8));
            float ex = expf(a0 - m) + expf(a1 - m) + expf(a2 - m) + expf(a3 - m) +
                       expf(a4 - m) + expf(a5 - m) + expf(a6 - m) + expf(a7 - m);
            ex += __shfl_xor(ex, 1);
            ex += __shfl_xor(ex, 2);
            ex += __shfl_xor(ex, 4);
            ex += __shfl_xor(ex, 8);
            float lse = m + logf(ex);
            if (sub == 0)
                *(float4*)(out + (size_t)node * 128 + fg * 8) = make_float4(a0 - lse, a1 - lse, a2 - lse, a3 - lse);
            else if (sub == 1)
                *(float4*)(out + (size_t)node * 128 + fg * 8 + 4) = make_float4(a4 - lse, a5 - lse, a6 - lse, a7 - lse);
        }
    }

    if (MODE == 0) {
        if (sub == 0) {
            atomicAdd(&stats[fg * 8 + 0], s0);
            atomicAdd(&stats[fg * 8 + 1], s1);
            atomicAdd(&stats[fg * 8 + 2], s2);
            atomicAdd(&stats[fg * 8 + 3], s3);
            atomicAdd(&stats[128 + fg * 8 + 0], q0);
            atomicAdd(&stats[128 + fg * 8 + 1], q1);
            atomicAdd(&stats[128 + fg * 8 + 2], q2);
            atomicAdd(&stats[128 + fg * 8 + 3], q3);
        } else if (sub == 1) {
            atomicAdd(&stats[fg * 8 + 4], s0);
            atomicAdd(&stats[fg * 8 + 5], s1);
            atomicAdd(&stats[fg * 8 + 6], s2);
            atomicAdd(&stats[fg * 8 + 7], s3);
            atomicAdd(&stats[128 + fg * 8 + 4], q0);
            atomicAdd(&stats[128 + fg * 8 + 5], q1);
            atomicAdd(&stats[128 + fg * 8 + 6], q2);
            atomicAdd(&stats[128 + fg * 8 + 7], q3);
        }
    }
}

// ---------------- BN finalize ----------------

__global__ void bnfin_k(const double* __restrict__ stats, const float* __restrict__ gamma,
                        const float* __restrict__ beta, float* __restrict__ ss, int n) {
    int f = threadIdx.x;
    if (f < 128) {
        double mu = stats[f] / n;
        double var = stats[128 + f] / n - mu * mu;
        float rs = rsqrtf((float)var + BN_EPS);
        float sc = gamma[f] * rs;
        ss[f] = sc;
        ss[128 + f] = beta[f] - (float)mu * sc;
    }
}

// ---------------- driver ----------------

extern "C" void kernel_launch(void* const* d_in, const int* in_sizes, int n_in,
                              void* d_out, int out_size, void* d_ws, size_t ws_size,
                              hipStream_t stream) {
    const float* x = (const float*)d_in[0];
    const int* ei = (const int*)d_in[1];
    const float* Ws = (const float*)d_in[2];
    const float* gammas = (const float*)d_in[3];
    const float* betas = (const float*)d_in[4];
    int N = in_sizes[0] / 128;
    int E = in_sizes[1] / 2;
    const int* src = ei;
    const int* dst = ei + E;
    float* out = (float*)d_out;

    char* w = (char*)d_ws;
    size_t o = 0;
    auto alloc = [&](size_t bytes) { char* p = w + o; o += (bytes + 511) & ~511ull; return p; };
    unsigned short* h = (unsigned short*)alloc((size_t)N * 128 * 2);  // bf16
    int* cnt = (int*)alloc((size_t)N * 4);
    int* rowptr = (int*)alloc(((size_t)N + 1) * 4);
    int* nxt = (int*)alloc((size_t)N * 4);
    int* bsum = (int*)alloc(4096);
    int* ssrc = (int*)alloc((size_t)E * 4);
    double* stats = (double*)alloc(512 * 8);
    float* ss = (float*)alloc(512 * 4);

    hipMemsetAsync(cnt, 0, (size_t)N * 4, stream);
    hipMemsetAsync(stats, 0, 512 * 8, stream);

    int ebl = (E + 255) / 256;
    int nb = (N + 1023) / 1024;
    count_k<<<ebl, 256, 0, stream>>>(dst, E, cnt);
    scan1_k<<<nb, 1024, 0, stream>>>(cnt, N, bsum);
    scan2_k<<<1, 64, 0, stream>>>(bsum, nb, rowptr, N, E);
    scan3_k<<<nb, 1024, 0, stream>>>(cnt, N, bsum, rowptr, nxt);
    scatter_k<<<ebl, 256, 0, stream>>>(src, dst, E, nxt, ssrc);

    int gblk = (N + 127) / 128;
    const int AGG_BLOCKS = 2048;

    gemm_k<0><<<gblk, 256, 0, stream>>>(x, Ws, h, nullptr, N);
    agg_k<0><<<AGG_BLOCKS, 256, 0, stream>>>(h, rowptr, ssrc, out, stats, N);
    bnfin_k<<<1, 128, 0, stream>>>(stats, gammas, betas, ss, N);
    gemm_k<1><<<gblk, 256, 0, stream>>>(out, Ws + 16384, h, ss, N);
    agg_k<0><<<AGG_BLOCKS, 256, 0, stream>>>(h, rowptr, ssrc, out, stats + 256, N);
    bnfin_k<<<1, 128, 0, stream>>>(stats + 256, gammas + 128, betas + 128, ss + 256, N);
    gemm_k<1><<<gblk, 256, 0, stream>>>(out, Ws + 32768, h, ss + 256, N);
    agg_k<1><<<AGG_BLOCKS, 256, 0, stream>>>(h, rowptr, ssrc, out, nullptr, N);
}

// Round 4
// 842.376 us; speedup vs baseline: 4.0935x; 4.0935x over previous
//
#include <hip/hip_runtime.h>

#define BN_EPS 1e-5f

// ---------------- CSR build ----------------

__global__ __launch_bounds__(256) void count_k(const int* __restrict__ dst, int E, int* __restrict__ cnt) {
    int i = blockIdx.x * 256 + threadIdx.x;
    if (i < E) atomicAdd(&cnt[dst[i]], 1);
}

__global__ __launch_bounds__(1024) void scan1_k(const int* __restrict__ cnt, int n, int* __restrict__ bsum) {
    __shared__ int sh[1024];
    int i = blockIdx.x * 1024 + threadIdx.x;
    sh[threadIdx.x] = (i < n) ? cnt[i] : 0;
    __syncthreads();
    for (int s = 512; s > 0; s >>= 1) {
        if (threadIdx.x < (unsigned)s) sh[threadIdx.x] += sh[threadIdx.x + s];
        __syncthreads();
    }
    if (threadIdx.x == 0) bsum[blockIdx.x] = sh[0];
}

__global__ void scan2_k(int* bsum, int nb, int* rowptr, int n, int E) {
    if (threadIdx.x == 0 && blockIdx.x == 0) {
        int run = 0;
        for (int i = 0; i < nb; ++i) { int v = bsum[i]; bsum[i] = run; run += v; }
        rowptr[n] = E;
    }
}

__global__ __launch_bounds__(1024) void scan3_k(const int* __restrict__ cnt, int n, const int* __restrict__ boff,
                                                int* __restrict__ rowptr, int* __restrict__ nxt) {
    __shared__ int sh[1024];
    int i = blockIdx.x * 1024 + threadIdx.x;
    int v = (i < n) ? cnt[i] : 0;
    sh[threadIdx.x] = v;
    __syncthreads();
    for (int s = 1; s < 1024; s <<= 1) {
        int t = (threadIdx.x >= (unsigned)s) ? sh[threadIdx.x - s] : 0;
        __syncthreads();
        sh[threadIdx.x] += t;
        __syncthreads();
    }
    if (i < n) {
        int ex = boff[blockIdx.x] + sh[threadIdx.x] - v;
        rowptr[i] = ex;
        nxt[i] = ex;
    }
}

__global__ __launch_bounds__(256) void scatter_k(const int* __restrict__ src, const int* __restrict__ dst, int E,
                                                 int* __restrict__ nxt, int* __restrict__ ssrc) {
    int i = blockIdx.x * 256 + threadIdx.x;
    if (i < E) {
        int d = dst[i];
        int p = atomicAdd(&nxt[d], 1);
        ssrc[p] = src[i];
    }
}

// ---------------- helpers ----------------

static __device__ __forceinline__ unsigned short f2bf(float f) {
    unsigned u = __float_as_uint(f);
    unsigned r = (u + 0x7FFFu + ((u >> 16) & 1u)) >> 16;  // RNE
    return (unsigned short)r;
}
static __device__ __forceinline__ float bf_lo(unsigned u) { return __uint_as_float(u << 16); }
static __device__ __forceinline__ float bf_hi(unsigned u) { return __uint_as_float(u & 0xFFFF0000u); }

// ---------------- GEMM: H(bf16) = f(X) @ W ----------------
// MODE 0: A = Xf (f32), f = identity.  MODE 1: A = Xb (bf16), f = BN+ReLU.

template <int MODE>
__global__ __launch_bounds__(256) void gemm_k(const float* __restrict__ Xf, const unsigned short* __restrict__ Xb,
                                              const float* __restrict__ W, unsigned short* __restrict__ H,
                                              const float* __restrict__ ss, int n) {
    __shared__ float As[128][36];
    __shared__ float Bs[32][128];
    int tid = threadIdx.x;
    int rg = tid & 15;
    int cg = tid >> 4;
    int rowBase = blockIdx.x * 128;

    float acc[8][8];
#pragma unroll
    for (int i = 0; i < 8; ++i)
#pragma unroll
        for (int j = 0; j < 8; ++j) acc[i][j] = 0.f;

    for (int k0 = 0; k0 < 128; k0 += 32) {
#pragma unroll
        for (int t = 0; t < 4; ++t) {
            int idx = tid + t * 256;
            int r = idx >> 3;
            int c4 = (idx & 7) * 4;
            int gr = rowBase + r;
            float4 v = make_float4(0.f, 0.f, 0.f, 0.f);
            if (gr < n) {
                if (MODE == 0) {
                    v = *(const float4*)(Xf + (size_t)gr * 128 + k0 + c4);
                } else {
                    uint2 u = *(const uint2*)(Xb + (size_t)gr * 128 + k0 + c4);
                    v = make_float4(bf_lo(u.x), bf_hi(u.x), bf_lo(u.y), bf_hi(u.y));
                    int c = k0 + c4;
                    v.x = fmaxf(fmaf(v.x, ss[c + 0], ss[128 + c + 0]), 0.f);
                    v.y = fmaxf(fmaf(v.y, ss[c + 1], ss[128 + c + 1]), 0.f);
                    v.z = fmaxf(fmaf(v.z, ss[c + 2], ss[128 + c + 2]), 0.f);
                    v.w = fmaxf(fmaf(v.w, ss[c + 3], ss[128 + c + 3]), 0.f);
                }
            }
            *(float4*)&As[r][c4] = v;
        }
#pragma unroll
        for (int t = 0; t < 4; ++t) {
            int idx = tid + t * 256;
            int r = idx >> 5;
            int c4 = (idx & 31) * 4;
            *(float4*)&Bs[r][c4] = *(const float4*)(W + (size_t)(k0 + r) * 128 + c4);
        }
        __syncthreads();

#pragma unroll
        for (int kk = 0; kk < 32; kk += 4) {
            float4 a[8];
#pragma unroll
            for (int i = 0; i < 8; ++i) a[i] = *(const float4*)&As[rg + 16 * i][kk];
#pragma unroll
            for (int t = 0; t < 4; ++t) {
                float4 wl = *(const float4*)&Bs[kk + t][cg * 8];
                float4 wh = *(const float4*)&Bs[kk + t][cg * 8 + 4];
#pragma unroll
                for (int i = 0; i < 8; ++i) {
                    float av = (t == 0) ? a[i].x : (t == 1) ? a[i].y : (t == 2) ? a[i].z : a[i].w;
                    acc[i][0] = fmaf(av, wl.x, acc[i][0]);
                    acc[i][1] = fmaf(av, wl.y, acc[i][1]);
                    acc[i][2] = fmaf(av, wl.z, acc[i][2]);
                    acc[i][3] = fmaf(av, wl.w, acc[i][3]);
                    acc[i][4] = fmaf(av, wh.x, acc[i][4]);
                    acc[i][5] = fmaf(av, wh.y, acc[i][5]);
                    acc[i][6] = fmaf(av, wh.z, acc[i][6]);
                    acc[i][7] = fmaf(av, wh.w, acc[i][7]);
                }
            }
        }
        __syncthreads();
    }

#pragma unroll
    for (int i = 0; i < 8; ++i) {
        int gr = rowBase + rg + 16 * i;
        if (gr < n) {
            uint4 pk;
            pk.x = (unsigned)f2bf(acc[i][0]) | ((unsigned)f2bf(acc[i][1]) << 16);
            pk.y = (unsigned)f2bf(acc[i][2]) | ((unsigned)f2bf(acc[i][3]) << 16);
            pk.z = (unsigned)f2bf(acc[i][4]) | ((unsigned)f2bf(acc[i][5]) << 16);
            pk.w = (unsigned)f2bf(acc[i][6]) | ((unsigned)f2bf(acc[i][7]) << 16);
            *(uint4*)(H + (size_t)gr * 128 + cg * 8) = pk;
        }
    }
}

// ---------------- Aggregation: wave per node, lane reads 2 bf16 feats (one unsigned) per edge ----------------
// 8-edge branch-free unroll: 8 independent 256B row-gathers in flight per iteration.
// MODE 0: write bf16 (packed) + f32 BN stats via LDS pre-reduce + float atomics.
// MODE 1: fused log_softmax, write f32.

template <int MODE>
__global__ __launch_bounds__(256) void agg_k(const unsigned short* __restrict__ H, const int* __restrict__ rowptr,
                                             const int* __restrict__ ssrc, unsigned* __restrict__ outb,
                                             float* __restrict__ outf, float* __restrict__ stats, int n) {
    __shared__ float sred[4][4][64];
    int lane = threadIdx.x & 63;
    int wv = threadIdx.x >> 6;
    int wid = (blockIdx.x * 256 + threadIdx.x) >> 6;
    int nw = (gridDim.x * 256) >> 6;
    const unsigned short* hb = H + 2 * lane;
    float s0 = 0, s1 = 0, q0 = 0, q1 = 0;

    for (int node = wid; node < n; node += nw) {
        int beg = rowptr[node], end = rowptr[node + 1];
        float ax = 0.f, ay = 0.f;
        int e = beg;
        for (; e + 8 <= end; e += 8) {
            int iA = ssrc[e + 0], iB = ssrc[e + 1], iC = ssrc[e + 2], iD = ssrc[e + 3];
            int iE = ssrc[e + 4], iF = ssrc[e + 5], iG = ssrc[e + 6], iH = ssrc[e + 7];
            unsigned v0 = *(const unsigned*)(hb + (size_t)iA * 128);
            unsigned v1 = *(const unsigned*)(hb + (size_t)iB * 128);
            unsigned v2 = *(const unsigned*)(hb + (size_t)iC * 128);
            unsigned v3 = *(const unsigned*)(hb + (size_t)iD * 128);
            unsigned v4 = *(const unsigned*)(hb + (size_t)iE * 128);
            unsigned v5 = *(const unsigned*)(hb + (size_t)iF * 128);
            unsigned v6 = *(const unsigned*)(hb + (size_t)iG * 128);
            unsigned v7 = *(const unsigned*)(hb + (size_t)iH * 128);
            ax += ((bf_lo(v0) + bf_lo(v1)) + (bf_lo(v2) + bf_lo(v3))) +
                  ((bf_lo(v4) + bf_lo(v5)) + (bf_lo(v6) + bf_lo(v7)));
            ay += ((bf_hi(v0) + bf_hi(v1)) + (bf_hi(v2) + bf_hi(v3))) +
                  ((bf_hi(v4) + bf_hi(v5)) + (bf_hi(v6) + bf_hi(v7)));
        }
        if (e + 4 <= end) {
            int iA = ssrc[e + 0], iB = ssrc[e + 1], iC = ssrc[e + 2], iD = ssrc[e + 3];
            unsigned v0 = *(const unsigned*)(hb + (size_t)iA * 128);
            unsigned v1 = *(const unsigned*)(hb + (size_t)iB * 128);
            unsigned v2 = *(const unsigned*)(hb + (size_t)iC * 128);
            unsigned v3 = *(const unsigned*)(hb + (size_t)iD * 128);
            ax += (bf_lo(v0) + bf_lo(v1)) + (bf_lo(v2) + bf_lo(v3));
            ay += (bf_hi(v0) + bf_hi(v1)) + (bf_hi(v2) + bf_hi(v3));
            e += 4;
        }
        for (; e < end; ++e) {
            unsigned v = *(const unsigned*)(hb + (size_t)ssrc[e] * 128);
            ax += bf_lo(v);
            ay += bf_hi(v);
        }

        if (MODE == 0) {
            outb[(size_t)node * 64 + lane] = (unsigned)f2bf(ax) | ((unsigned)f2bf(ay) << 16);
            s0 += ax; q0 += ax * ax;
            s1 += ay; q1 += ay * ay;
        } else {
            float m = fmaxf(ax, ay);
#pragma unroll
            for (int off = 32; off > 0; off >>= 1) m = fmaxf(m, __shfl_xor(m, off));
            float ex = expf(ax - m) + expf(ay - m);
#pragma unroll
            for (int off = 32; off > 0; off >>= 1) ex += __shfl_xor(ex, off);
            float lse = m + logf(ex);
            *(float2*)(outf + (size_t)node * 128 + 2 * lane) = make_float2(ax - lse, ay - lse);
        }
    }

    if (MODE == 0) {
        sred[wv][0][lane] = s0;
        sred[wv][1][lane] = s1;
        sred[wv][2][lane] = q0;
        sred[wv][3][lane] = q1;
        __syncthreads();
        if (wv == 0) {
            float t0 = (sred[0][0][lane] + sred[1][0][lane]) + (sred[2][0][lane] + sred[3][0][lane]);
            float t1 = (sred[0][1][lane] + sred[1][1][lane]) + (sred[2][1][lane] + sred[3][1][lane]);
            float t2 = (sred[0][2][lane] + sred[1][2][lane]) + (sred[2][2][lane] + sred[3][2][lane]);
            float t3 = (sred[0][3][lane] + sred[1][3][lane]) + (sred[2][3][lane] + sred[3][3][lane]);
            atomicAdd(&stats[2 * lane], t0);
            atomicAdd(&stats[2 * lane + 1], t1);
            atomicAdd(&stats[128 + 2 * lane], t2);
            atomicAdd(&stats[128 + 2 * lane + 1], t3);
        }
    }
}

// ---------------- BN finalize ----------------

__global__ void bnfin_k(const float* __restrict__ stats, const float* __restrict__ gamma,
                        const float* __restrict__ beta, float* __restrict__ ss, int n) {
    int f = threadIdx.x;
    if (f < 128) {
        float mu = stats[f] / n;
        float var = stats[128 + f] / n - mu * mu;
        float rs = rsqrtf(fmaxf(var, 0.f) + BN_EPS);
        float sc = gamma[f] * rs;
        ss[f] = sc;
        ss[128 + f] = beta[f] - mu * sc;
    }
}

// ---------------- driver ----------------

extern "C" void kernel_launch(void* const* d_in, const int* in_sizes, int n_in,
                              void* d_out, int out_size, void* d_ws, size_t ws_size,
                              hipStream_t stream) {
    const float* x = (const float*)d_in[0];
    const int* ei = (const int*)d_in[1];
    const float* Ws = (const float*)d_in[2];
    const float* gammas = (const float*)d_in[3];
    const float* betas = (const float*)d_in[4];
    int N = in_sizes[0] / 128;
    int E = in_sizes[1] / 2;
    const int* src = ei;
    const int* dst = ei + E;
    float* out = (float*)d_out;

    char* w = (char*)d_ws;
    size_t o = 0;
    auto alloc = [&](size_t bytes) { char* p = w + o; o += (bytes + 511) & ~511ull; return p; };
    unsigned short* h = (unsigned short*)alloc((size_t)N * 128 * 2);   // bf16 GEMM out / agg in
    unsigned short* h2 = (unsigned short*)alloc((size_t)N * 128 * 2);  // bf16 agg out / GEMM in
    int* cnt = (int*)alloc((size_t)N * 4);
    int* rowptr = (int*)alloc(((size_t)N + 1) * 4);
    int* nxt = (int*)alloc((size_t)N * 4);
    int* bsum = (int*)alloc(4096);
    int* ssrc = (int*)alloc((size_t)E * 4);
    float* stats = (float*)alloc(512 * 4);  // [sum128|sq128] x 2 layers
    float* ss = (float*)alloc(512 * 4);     // [scale128|shift128] x 2 layers

    hipMemsetAsync(cnt, 0, (size_t)N * 4, stream);
    hipMemsetAsync(stats, 0, 512 * 4, stream);

    int ebl = (E + 255) / 256;
    int nb = (N + 1023) / 1024;
    count_k<<<ebl, 256, 0, stream>>>(dst, E, cnt);
    scan1_k<<<nb, 1024, 0, stream>>>(cnt, N, bsum);
    scan2_k<<<1, 64, 0, stream>>>(bsum, nb, rowptr, N, E);
    scan3_k<<<nb, 1024, 0, stream>>>(cnt, N, bsum, rowptr, nxt);
    scatter_k<<<ebl, 256, 0, stream>>>(src, dst, E, nxt, ssrc);

    int gblk = (N + 127) / 128;
    const int AGG_BLOCKS = 2048;

    gemm_k<0><<<gblk, 256, 0, stream>>>(x, nullptr, Ws, h, nullptr, N);
    agg_k<0><<<AGG_BLOCKS, 256, 0, stream>>>(h, rowptr, ssrc, (unsigned*)h2, nullptr, stats, N);
    bnfin_k<<<1, 128, 0, stream>>>(stats, gammas, betas, ss, N);
    gemm_k<1><<<gblk, 256, 0, stream>>>(nullptr, h2, Ws + 16384, h, ss, N);
    agg_k<0><<<AGG_BLOCKS, 256, 0, stream>>>(h, rowptr, ssrc, (unsigned*)h2, nullptr, stats + 256, N);
    bnfin_k<<<1, 128, 0, stream>>>(stats + 256, gammas + 128, betas + 128, ss + 256, N);
    gemm_k<1><<<gblk, 256, 0, stream>>>(nullptr, h2, Ws + 32768, h, ss + 256, N);
    agg_k<1><<<AGG_BLOCKS, 256, 0, stream>>>(h, rowptr, ssrc, nullptr, out, nullptr, N);
}

// Round 5
// 738.943 us; speedup vs baseline: 4.6665x; 1.1400x over previous
//
#include <hip/hip_runtime.h>

#define BN_EPS 1e-5f

typedef __attribute__((ext_vector_type(8))) short bf16x8;
typedef __attribute__((ext_vector_type(4))) float f32x4;

union VU {
    uint4 u;
    bf16x8 b;
};

// ---------------- CSR build ----------------

__global__ __launch_bounds__(256) void count_k(const int* __restrict__ dst, int E, int* __restrict__ cnt) {
    int i = blockIdx.x * 256 + threadIdx.x;
    if (i < E) atomicAdd(&cnt[dst[i]], 1);
}

__global__ __launch_bounds__(1024) void scan1_k(const int* __restrict__ cnt, int n, int* __restrict__ bsum) {
    __shared__ int sh[1024];
    int i = blockIdx.x * 1024 + threadIdx.x;
    sh[threadIdx.x] = (i < n) ? cnt[i] : 0;
    __syncthreads();
    for (int s = 512; s > 0; s >>= 1) {
        if (threadIdx.x < (unsigned)s) sh[threadIdx.x] += sh[threadIdx.x + s];
        __syncthreads();
    }
    if (threadIdx.x == 0) bsum[blockIdx.x] = sh[0];
}

__global__ void scan2_k(int* bsum, int nb, int* rowptr, int n, int E) {
    if (threadIdx.x == 0 && blockIdx.x == 0) {
        int run = 0;
        for (int i = 0; i < nb; ++i) { int v = bsum[i]; bsum[i] = run; run += v; }
        rowptr[n] = E;
    }
}

__global__ __launch_bounds__(1024) void scan3_k(const int* __restrict__ cnt, int n, const int* __restrict__ boff,
                                                int* __restrict__ rowptr, int* __restrict__ nxt) {
    __shared__ int sh[1024];
    int i = blockIdx.x * 1024 + threadIdx.x;
    int v = (i < n) ? cnt[i] : 0;
    sh[threadIdx.x] = v;
    __syncthreads();
    for (int s = 1; s < 1024; s <<= 1) {
        int t = (threadIdx.x >= (unsigned)s) ? sh[threadIdx.x - s] : 0;
        __syncthreads();
        sh[threadIdx.x] += t;
        __syncthreads();
    }
    if (i < n) {
        int ex = boff[blockIdx.x] + sh[threadIdx.x] - v;
        rowptr[i] = ex;
        nxt[i] = ex;
    }
}

__global__ __launch_bounds__(256) void scatter_k(const int* __restrict__ src, const int* __restrict__ dst, int E,
                                                 int* __restrict__ nxt, int* __restrict__ ssrc) {
    int i = blockIdx.x * 256 + threadIdx.x;
    if (i < E) {
        int d = dst[i];
        int p = atomicAdd(&nxt[d], 1);
        ssrc[p] = src[i];
    }
}

// ---------------- helpers ----------------

static __device__ __forceinline__ unsigned short f2bf(float f) {
    unsigned u = __float_as_uint(f);
    unsigned r = (u + 0x7FFFu + ((u >> 16) & 1u)) >> 16;  // RNE
    return (unsigned short)r;
}
static __device__ __forceinline__ float bf_lo(unsigned u) { return __uint_as_float(u << 16); }
static __device__ __forceinline__ float bf_hi(unsigned u) { return __uint_as_float(u & 0xFFFF0000u); }

// ---------------- prep: pack W (3 layers f32 128x128) into bf16 MFMA B-fragments ----------------
// Wp[L][kt][nt][lane] (uint4 = 8 bf16): W[L][k = kt*32 + (lane>>4)*8 + j][n = nt*16 + (lane&15)]

__global__ __launch_bounds__(256) void prepw_k(const float* __restrict__ Ws, uint4* __restrict__ Wp) {
    int id = blockIdx.x * 256 + threadIdx.x;
    if (id >= 3 * 4 * 8 * 64) return;
    int lane = id & 63;
    int nt = (id >> 6) & 7;
    int kt = (id >> 9) & 3;
    int L = id >> 11;
    int quad = lane >> 4, l16 = lane & 15;
    const float* wsrc = Ws + L * 16384 + (kt * 32 + quad * 8) * 128 + nt * 16 + l16;
    unsigned short s[8];
#pragma unroll
    for (int j = 0; j < 8; ++j) s[j] = f2bf(wsrc[j * 128]);
    uint4 pk;
    pk.x = (unsigned)s[0] | ((unsigned)s[1] << 16);
    pk.y = (unsigned)s[2] | ((unsigned)s[3] << 16);
    pk.z = (unsigned)s[4] | ((unsigned)s[5] << 16);
    pk.w = (unsigned)s[6] | ((unsigned)s[7] << 16);
    Wp[id] = pk;
}

// ---------------- prep: x f32 -> bf16 ----------------

__global__ __launch_bounds__(256) void cvt_k(const float* __restrict__ x, unsigned* __restrict__ xb, long n4) {
    long i = (long)blockIdx.x * 256 + threadIdx.x;
    long stride = (long)gridDim.x * 256;
    for (; i < n4; i += stride) {
        float4 v = *(const float4*)(x + i * 4);
        uint2 pk;
        pk.x = (unsigned)f2bf(v.x) | ((unsigned)f2bf(v.y) << 16);
        pk.y = (unsigned)f2bf(v.z) | ((unsigned)f2bf(v.w) << 16);
        *(uint2*)(xb + i * 2) = pk;
    }
}

// ---------------- BN+ReLU elementwise on bf16 buffer ----------------

__global__ __launch_bounds__(256) void bnrelu_k(unsigned* __restrict__ h, const float* __restrict__ ss, long n4) {
    long i = (long)blockIdx.x * 256 + threadIdx.x;
    long stride = (long)gridDim.x * 256;
    for (; i < n4; i += stride) {
        int col = (int)((i * 4) & 127);
        uint2 v = *(uint2*)(h + i * 2);
        float4 sc = *(const float4*)(ss + col);
        float4 sh = *(const float4*)(ss + 128 + col);
        float v0 = fmaxf(fmaf(bf_lo(v.x), sc.x, sh.x), 0.f);
        float v1 = fmaxf(fmaf(bf_hi(v.x), sc.y, sh.y), 0.f);
        float v2 = fmaxf(fmaf(bf_lo(v.y), sc.z, sh.z), 0.f);
        float v3 = fmaxf(fmaf(bf_hi(v.y), sc.w, sh.w), 0.f);
        uint2 pk;
        pk.x = (unsigned)f2bf(v0) | ((unsigned)f2bf(v1) << 16);
        pk.y = (unsigned)f2bf(v2) | ((unsigned)f2bf(v3) << 16);
        *(uint2*)(h + i * 2) = pk;
    }
}

// ---------------- MFMA GEMM: H(bf16) = X(bf16) @ Wp ----------------
// Wave-per-16-row-tile, grid-strided. All of W resident in registers (4x8 uint4).
// mfma(Wfrag, Xfrag, acc) computes (X@W)^T: C col=lane&15 -> H row, C row=quad*4+r -> H col.

__global__ __launch_bounds__(256) void mgemm_k(const unsigned short* __restrict__ X, const uint4* __restrict__ Wp,
                                               unsigned short* __restrict__ H, int n) {
    int lane = threadIdx.x & 63;
    int quad = lane >> 4, l16 = lane & 15;
    int wid = (blockIdx.x * 256 + threadIdx.x) >> 6;
    int nw = (gridDim.x * 256) >> 6;
    int ntiles = (n + 15) >> 4;

    VU b[4][8];
#pragma unroll
    for (int kt = 0; kt < 4; ++kt)
#pragma unroll
        for (int nt = 0; nt < 8; ++nt) b[kt][nt].u = Wp[(kt * 8 + nt) * 64 + lane];

    int t = wid;
    VU a[4];
    if (t < ntiles) {
        int row = t * 16 + l16;
        const uint4* xr = (const uint4*)(X + (size_t)row * 128);
#pragma unroll
        for (int kt = 0; kt < 4; ++kt) a[kt].u = xr[kt * 4 + quad];
    }

    while (t < ntiles) {
        int tn = t + nw;
        VU an[4];
        if (tn < ntiles) {
            int row = tn * 16 + l16;
            const uint4* xr = (const uint4*)(X + (size_t)row * 128);
#pragma unroll
            for (int kt = 0; kt < 4; ++kt) an[kt].u = xr[kt * 4 + quad];
        }

        f32x4 acc[8];
#pragma unroll
        for (int nt = 0; nt < 8; ++nt) acc[nt] = (f32x4){0.f, 0.f, 0.f, 0.f};
#pragma unroll
        for (int kt = 0; kt < 4; ++kt)
#pragma unroll
            for (int nt = 0; nt < 8; ++nt)
                acc[nt] = __builtin_amdgcn_mfma_f32_16x16x32_bf16(b[kt][nt].b, a[kt].b, acc[nt], 0, 0, 0);

        unsigned short* hp = H + (size_t)(t * 16 + l16) * 128 + quad * 4;
#pragma unroll
        for (int nt = 0; nt < 8; ++nt) {
            uint2 pk;
            pk.x = (unsigned)f2bf(acc[nt][0]) | ((unsigned)f2bf(acc[nt][1]) << 16);
            pk.y = (unsigned)f2bf(acc[nt][2]) | ((unsigned)f2bf(acc[nt][3]) << 16);
            *(uint2*)(hp + nt * 16) = pk;
        }

#pragma unroll
        for (int kt = 0; kt < 4; ++kt) a[kt] = an[kt];
        t = tn;
    }
}

// ---------------- Aggregation (unchanged R4 structure) ----------------

template <int MODE>
__global__ __launch_bounds__(256) void agg_k(const unsigned short* __restrict__ H, const int* __restrict__ rowptr,
                                             const int* __restrict__ ssrc, unsigned* __restrict__ outb,
                                             float* __restrict__ outf, float* __restrict__ stats, int n) {
    __shared__ float sred[4][4][64];
    int lane = threadIdx.x & 63;
    int wv = threadIdx.x >> 6;
    int wid = (blockIdx.x * 256 + threadIdx.x) >> 6;
    int nw = (gridDim.x * 256) >> 6;
    const unsigned short* hb = H + 2 * lane;
    float s0 = 0, s1 = 0, q0 = 0, q1 = 0;

    for (int node = wid; node < n; node += nw) {
        int beg = rowptr[node], end = rowptr[node + 1];
        float ax = 0.f, ay = 0.f;
        int e = beg;
        for (; e + 8 <= end; e += 8) {
            int iA = ssrc[e + 0], iB = ssrc[e + 1], iC = ssrc[e + 2], iD = ssrc[e + 3];
            int iE = ssrc[e + 4], iF = ssrc[e + 5], iG = ssrc[e + 6], iH = ssrc[e + 7];
            unsigned v0 = *(const unsigned*)(hb + (size_t)iA * 128);
            unsigned v1 = *(const unsigned*)(hb + (size_t)iB * 128);
            unsigned v2 = *(const unsigned*)(hb + (size_t)iC * 128);
            unsigned v3 = *(const unsigned*)(hb + (size_t)iD * 128);
            unsigned v4 = *(const unsigned*)(hb + (size_t)iE * 128);
            unsigned v5 = *(const unsigned*)(hb + (size_t)iF * 128);
            unsigned v6 = *(const unsigned*)(hb + (size_t)iG * 128);
            unsigned v7 = *(const unsigned*)(hb + (size_t)iH * 128);
            ax += ((bf_lo(v0) + bf_lo(v1)) + (bf_lo(v2) + bf_lo(v3))) +
                  ((bf_lo(v4) + bf_lo(v5)) + (bf_lo(v6) + bf_lo(v7)));
            ay += ((bf_hi(v0) + bf_hi(v1)) + (bf_hi(v2) + bf_hi(v3))) +
                  ((bf_hi(v4) + bf_hi(v5)) + (bf_hi(v6) + bf_hi(v7)));
        }
        if (e + 4 <= end) {
            int iA = ssrc[e + 0], iB = ssrc[e + 1], iC = ssrc[e + 2], iD = ssrc[e + 3];
            unsigned v0 = *(const unsigned*)(hb + (size_t)iA * 128);
            unsigned v1 = *(const unsigned*)(hb + (size_t)iB * 128);
            unsigned v2 = *(const unsigned*)(hb + (size_t)iC * 128);
            unsigned v3 = *(const unsigned*)(hb + (size_t)iD * 128);
            ax += (bf_lo(v0) + bf_lo(v1)) + (bf_lo(v2) + bf_lo(v3));
            ay += (bf_hi(v0) + bf_hi(v1)) + (bf_hi(v2) + bf_hi(v3));
            e += 4;
        }
        for (; e < end; ++e) {
            unsigned v = *(const unsigned*)(hb + (size_t)ssrc[e] * 128);
            ax += bf_lo(v);
            ay += bf_hi(v);
        }

        if (MODE == 0) {
            outb[(size_t)node * 64 + lane] = (unsigned)f2bf(ax) | ((unsigned)f2bf(ay) << 16);
            s0 += ax; q0 += ax * ax;
            s1 += ay; q1 += ay * ay;
        } else {
            float m = fmaxf(ax, ay);
#pragma unroll
            for (int off = 32; off > 0; off >>= 1) m = fmaxf(m, __shfl_xor(m, off));
            float ex = expf(ax - m) + expf(ay - m);
#pragma unroll
            for (int off = 32; off > 0; off >>= 1) ex += __shfl_xor(ex, off);
            float lse = m + logf(ex);
            *(float2*)(outf + (size_t)node * 128 + 2 * lane) = make_float2(ax - lse, ay - lse);
        }
    }

    if (MODE == 0) {
        sred[wv][0][lane] = s0;
        sred[wv][1][lane] = s1;
        sred[wv][2][lane] = q0;
        sred[wv][3][lane] = q1;
        __syncthreads();
        if (wv == 0) {
            float t0 = (sred[0][0][lane] + sred[1][0][lane]) + (sred[2][0][lane] + sred[3][0][lane]);
            float t1 = (sred[0][1][lane] + sred[1][1][lane]) + (sred[2][1][lane] + sred[3][1][lane]);
            float t2 = (sred[0][2][lane] + sred[1][2][lane]) + (sred[2][2][lane] + sred[3][2][lane]);
            float t3 = (sred[0][3][lane] + sred[1][3][lane]) + (sred[2][3][lane] + sred[3][3][lane]);
            atomicAdd(&stats[2 * lane], t0);
            atomicAdd(&stats[2 * lane + 1], t1);
            atomicAdd(&stats[128 + 2 * lane], t2);
            atomicAdd(&stats[128 + 2 * lane + 1], t3);
        }
    }
}

// ---------------- BN finalize ----------------

__global__ void bnfin_k(const float* __restrict__ stats, const float* __restrict__ gamma,
                        const float* __restrict__ beta, float* __restrict__ ss, int n) {
    int f = threadIdx.x;
    if (f < 128) {
        float mu = stats[f] / n;
        float var = stats[128 + f] / n - mu * mu;
        float rs = rsqrtf(fmaxf(var, 0.f) + BN_EPS);
        float sc = gamma[f] * rs;
        ss[f] = sc;
        ss[128 + f] = beta[f] - mu * sc;
    }
}

// ---------------- driver ----------------

extern "C" void kernel_launch(void* const* d_in, const int* in_sizes, int n_in,
                              void* d_out, int out_size, void* d_ws, size_t ws_size,
                              hipStream_t stream) {
    const float* x = (const float*)d_in[0];
    const int* ei = (const int*)d_in[1];
    const float* Ws = (const float*)d_in[2];
    const float* gammas = (const float*)d_in[3];
    const float* betas = (const float*)d_in[4];
    int N = in_sizes[0] / 128;
    int E = in_sizes[1] / 2;
    const int* src = ei;
    const int* dst = ei + E;
    float* out = (float*)d_out;

    char* w = (char*)d_ws;
    size_t o = 0;
    auto alloc = [&](size_t bytes) { char* p = w + o; o += (bytes + 511) & ~511ull; return p; };
    unsigned short* h = (unsigned short*)alloc((size_t)N * 128 * 2);   // bf16 GEMM out / agg in
    unsigned short* h2 = (unsigned short*)alloc((size_t)N * 128 * 2);  // bf16 agg out / GEMM in
    unsigned short* xb = (unsigned short*)alloc((size_t)N * 128 * 2);  // bf16 x
    int* cnt = (int*)alloc((size_t)N * 4);
    int* rowptr = (int*)alloc(((size_t)N + 1) * 4);
    int* nxt = (int*)alloc((size_t)N * 4);
    int* bsum = (int*)alloc(4096);
    int* ssrc = (int*)alloc((size_t)E * 4);
    uint4* Wp = (uint4*)alloc(3 * 2048 * 16);  // packed bf16 W fragments
    float* stats = (float*)alloc(512 * 4);
    float* ss = (float*)alloc(512 * 4);

    hipMemsetAsync(cnt, 0, (size_t)N * 4, stream);
    hipMemsetAsync(stats, 0, 512 * 4, stream);

    int ebl = (E + 255) / 256;
    int nb = (N + 1023) / 1024;
    prepw_k<<<24, 256, 0, stream>>>(Ws, Wp);
    cvt_k<<<2048, 256, 0, stream>>>(x, (unsigned*)xb, (long)N * 32);
    count_k<<<ebl, 256, 0, stream>>>(dst, E, cnt);
    scan1_k<<<nb, 1024, 0, stream>>>(cnt, N, bsum);
    scan2_k<<<1, 64, 0, stream>>>(bsum, nb, rowptr, N, E);
    scan3_k<<<nb, 1024, 0, stream>>>(cnt, N, bsum, rowptr, nxt);
    scatter_k<<<ebl, 256, 0, stream>>>(src, dst, E, nxt, ssrc);

    const int AGG_BLOCKS = 2048;
    const int GEMM_BLOCKS = 512;
    long n4 = (long)N * 32;

    mgemm_k<<<GEMM_BLOCKS, 256, 0, stream>>>(xb, Wp, h, N);
    agg_k<0><<<AGG_BLOCKS, 256, 0, stream>>>(h, rowptr, ssrc, (unsigned*)h2, nullptr, stats, N);
    bnfin_k<<<1, 128, 0, stream>>>(stats, gammas, betas, ss, N);
    bnrelu_k<<<1024, 256, 0, stream>>>((unsigned*)h2, ss, n4);
    mgemm_k<<<GEMM_BLOCKS, 256, 0, stream>>>(h2, Wp + 2048, h, N);
    agg_k<0><<<AGG_BLOCKS, 256, 0, stream>>>(h, rowptr, ssrc, (unsigned*)h2, nullptr, stats + 256, N);
    bnfin_k<<<1, 128, 0, stream>>>(stats + 256, gammas + 128, betas + 128, ss + 256, N);
    bnrelu_k<<<1024, 256, 0, stream>>>((unsigned*)h2, ss + 256, n4);
    mgemm_k<<<GEMM_BLOCKS, 256, 0, stream>>>(h2, Wp + 4096, h, N);
    agg_k<1><<<AGG_BLOCKS, 256, 0, stream>>>(h, rowptr, ssrc, nullptr, out, nullptr, N);
}